// Round 13
// baseline (513.101 us; speedup 1.0000x reference)
//
#include <hip/hip_runtime.h>
#include <hip/hip_bf16.h>
#include <math.h>

// Problem constants
#define B_  4
#define L_  2048
#define D_  2048
#define H_  16
#define HD_ 128
#define BH_ (B_*H_)   // 64
#define BL_ (B_*L_)   // 8192

typedef __attribute__((ext_vector_type(4))) float  f32x4;
typedef __attribute__((ext_vector_type(8))) __bf16 bf16x8;

static __device__ __forceinline__ float bf2f(unsigned short u) {
    union { unsigned int i; float f; } v; v.i = ((unsigned int)u) << 16; return v.f;
}
static __device__ __forceinline__ unsigned short f2bf(float f) {
    union { float f; unsigned int i; } v; v.f = f;
    unsigned int x = v.i;
    return (unsigned short)((x + 0x7fffu + ((x >> 16) & 1u)) >> 16);  // RNE
}

// async global->LDS, 16B per lane. lds base must be wave-uniform; HW scatters +lane*16B.
static __device__ __forceinline__ void gload16(const unsigned short* g, unsigned short* l) {
    __builtin_amdgcn_global_load_lds(
        (const __attribute__((address_space(1))) unsigned int*)(const void*)g,
        (__attribute__((address_space(3))) unsigned int*)(void*)l, 16, 0, 0);
}

// ---------------------------------------------------------------- convert x -> bf16
__global__ __launch_bounds__(256) void k_f32_to_bf16(const float* __restrict__ s,
                                                     unsigned short* __restrict__ d, int n8) {
    int i = blockIdx.x * 256 + threadIdx.x;
    if (i >= n8) return;
    const float* p = s + (size_t)i * 8;
    float4 a = *(const float4*)p;
    float4 b = *(const float4*)(p + 4);
    union { bf16x8 v; unsigned short u[8]; } o;
    o.u[0]=f2bf(a.x); o.u[1]=f2bf(a.y); o.u[2]=f2bf(a.z); o.u[3]=f2bf(a.w);
    o.u[4]=f2bf(b.x); o.u[5]=f2bf(b.y); o.u[6]=f2bf(b.z); o.u[7]=f2bf(b.w);
    *(bf16x8*)(d + (size_t)i * 8) = o.v;
}

// ---------------------------------------------------------------- transpose f32 -> bf16
__global__ __launch_bounds__(256) void k_transpose_f2b(const float* __restrict__ src,
                                                       unsigned short* __restrict__ dst,
                                                       int R, int C, int dstStride) {
    __shared__ float tile[32][33];
    int tx = threadIdx.x & 31, ty = threadIdx.x >> 5;   // 32 x 8
    int c0 = blockIdx.x * 32, r0 = blockIdx.y * 32;
    #pragma unroll
    for (int i = 0; i < 32; i += 8)
        tile[ty + i][tx] = src[(size_t)(r0 + ty + i) * C + c0 + tx];
    __syncthreads();
    #pragma unroll
    for (int i = 0; i < 32; i += 8)
        dst[(size_t)(c0 + ty + i) * dstStride + r0 + tx] = f2bf(tile[tx][ty + i]);
}

// ---------------------------------------------------------------- 128x128 GEMM, 2 blocks/CU
// C = A @ Bt^T. 256 thr / 4 waves (2M x 2N, per-wave 64x64), BK=64.
// LDS 64 KB (2dbuf x {A,B} x 16KB) -> 2 blocks/CU: two INDEPENDENT barrier
// domains per CU; one block's MFMA fills the other's barrier/wait stalls (m114).
// Schedule per K-tile (reads for t issued at end of prior iter):
//   lgkm(0) [t-frags in regs] -> b1 [Lds[c] free] -> stage t+2 -> 32 MFMA
//   -> vmcnt(8|0) [t+1 landed] -> b2 -> reads t+1 from Lds[cn]
// Ledger: vmcnt(8) leaves exactly t+2's 8 stage-ops; stage t+2 -> Lds[c] is WAR-gated
// by b1; reads of t+1 precede next b1, and Lds[cn]'s next writer (stage t+3) follows it.
// XOR slot swizzle on SOURCE addr and READ (linear gload_lds dest) -- rule 21.

static __device__ __forceinline__ void ds_load4(const unsigned short* u, int half,
                                                int l15, int l4, bf16x8 (&fr)[4][2]) {
    int sw = l15 & 7;
    #pragma unroll
    for (int i = 0; i < 4; ++i) {
        int ro = (half*64 + i*16 + l15) * 64;
        fr[i][0] = *(const bf16x8*)(u + ro + ((l4 ^ sw) << 3));
        fr[i][1] = *(const bf16x8*)(u + ro + (((4 + l4) ^ sw) << 3));
    }
}

#define SB_() __builtin_amdgcn_sched_barrier(0)
// stage one 128x64 tile pair (A,B) for K-tile t_ into dbuf c_: 8 gloads/thread
// (manually unrolled; #pragma is illegal inside a macro body)
#define STAGE_T_(c_, t_) do {                                                         \
    gload16(gA + (size_t)(0*32) * 2048 + (t_)*64, &Lds[c_][0][0*2048 + w*512]);       \
    gload16(gB + (size_t)(0*32) * 2048 + (t_)*64, &Lds[c_][1][0*2048 + w*512]);       \
    gload16(gA + (size_t)(1*32) * 2048 + (t_)*64, &Lds[c_][0][1*2048 + w*512]);       \
    gload16(gB + (size_t)(1*32) * 2048 + (t_)*64, &Lds[c_][1][1*2048 + w*512]);       \
    gload16(gA + (size_t)(2*32) * 2048 + (t_)*64, &Lds[c_][0][2*2048 + w*512]);       \
    gload16(gB + (size_t)(2*32) * 2048 + (t_)*64, &Lds[c_][1][2*2048 + w*512]);       \
    gload16(gA + (size_t)(3*32) * 2048 + (t_)*64, &Lds[c_][0][3*2048 + w*512]);       \
    gload16(gB + (size_t)(3*32) * 2048 + (t_)*64, &Lds[c_][1][3*2048 + w*512]);       \
} while (0)

template<int MODE>
__global__ __launch_bounds__(256, 2) void k_gemm(const unsigned short* __restrict__ A,
                                                 const unsigned short* __restrict__ Bt,
                                                 int M, int N, int K,
                                                 const float* __restrict__ bias,
                                                 unsigned short* __restrict__ qout,
                                                 unsigned short* __restrict__ kout,
                                                 unsigned short* __restrict__ vout,
                                                 float* __restrict__ fout) {
    (void)K;
    __shared__ __align__(16) unsigned short Lds[2][2][8192];  // [dbuf][A/B][16KB]
    const int tid = threadIdx.x;
    const int lane = tid & 63, w = tid >> 6;      // 4 waves
    const int wm = w >> 1, wn = w & 1;            // 2M x 2N
    const int l15 = lane & 15, l4 = lane >> 4;
    const int lsw = (lane & 7) ^ ((lane >> 3) & 7);

    int nwgx = gridDim.x;
    int bid = blockIdx.y * nwgx + blockIdx.x;
    int cpx = (nwgx * gridDim.y) >> 3;
    int sb = (bid & 7) * cpx + (bid >> 3);
    int n0 = (sb % nwgx) * 128, m0 = (sb / nwgx) * 128;

    // per-lane staging source bases: thread covers row (tid>>3) of 128, pre-swizzled col
    const unsigned short* gA = A  + (size_t)(m0 + (tid >> 3)) * 2048 + lsw*8;
    const unsigned short* gB = Bt + (size_t)(n0 + (tid >> 3)) * 2048 + lsw*8;

    f32x4 acc[4][4] = {};
    bf16x8 afr[4][2], bfr[4][2];
    const int nt = 2048 / 64;  // 32 K-tiles

    // ---- prologue: stage T0, T1; drain T0; read T0
    STAGE_T_(0, 0);
    STAGE_T_(1, 1);
    asm volatile("s_waitcnt vmcnt(8)" ::: "memory");
    __builtin_amdgcn_s_barrier();
    ds_load4(&Lds[0][0][0], wm, l15, l4, afr);
    ds_load4(&Lds[0][1][0], wn, l15, l4, bfr);
    SB_();

    for (int t = 0; t < nt; ++t) {
        const int c = t & 1, cn = c ^ 1;
        const bool h1 = (t + 1 < nt), h2 = (t + 2 < nt);

        asm volatile("s_waitcnt lgkmcnt(0)" ::: "memory");  // tile t frags in regs
        SB_();
        __builtin_amdgcn_s_barrier();                       // b1: Lds[c] free
        if (h2) STAGE_T_(c, t + 2);
        __builtin_amdgcn_s_setprio(1);
        #pragma unroll
        for (int mi = 0; mi < 4; ++mi)
            #pragma unroll
            for (int ni = 0; ni < 4; ++ni) {
                acc[mi][ni] = __builtin_amdgcn_mfma_f32_16x16x32_bf16(
                    afr[mi][0], bfr[ni][0], acc[mi][ni], 0, 0, 0);
                acc[mi][ni] = __builtin_amdgcn_mfma_f32_16x16x32_bf16(
                    afr[mi][1], bfr[ni][1], acc[mi][ni], 0, 0, 0);
            }
        __builtin_amdgcn_s_setprio(0);
        SB_();
        if (h2) asm volatile("s_waitcnt vmcnt(8)" ::: "memory");
        else    asm volatile("s_waitcnt vmcnt(0)" ::: "memory");
        __builtin_amdgcn_s_barrier();                       // b2: tile t+1 landed
        if (h1) {
            ds_load4(&Lds[cn][0][0], wm, l15, l4, afr);
            ds_load4(&Lds[cn][1][0], wn, l15, l4, bfr);
            SB_();
        }
    }

    // ---- epilogue; MODE 0 writes V TRANSPOSED (BH,HD,L) directly (8B packed j-quad)
    #pragma unroll
    for (int mi = 0; mi < 4; ++mi) {
        #pragma unroll
        for (int ni = 0; ni < 4; ++ni) {
            int ncol = n0 + wn*64 + ni*16 + l15;
            int mbase = m0 + wm*64 + mi*16 + l4*4;
            if (MODE == 0 && ncol >= 4096) {
                int cc = ncol - 4096, h = cc >> 7, hd = cc & 127;
                int b = mbase >> 11, l = mbase & 2047;   // 4 consecutive l, same b
                float bv = bias[cc];
                ushort4 o;
                o.x = f2bf(acc[mi][ni][0] + bv);
                o.y = f2bf(acc[mi][ni][1] + bv);
                o.z = f2bf(acc[mi][ni][2] + bv);
                o.w = f2bf(acc[mi][ni][3] + bv);
                *(ushort4*)(vout + ((size_t)((b*H_ + h) * HD_ + hd)) * L_ + l) = o;
            } else {
                #pragma unroll
                for (int j = 0; j < 4; ++j) {
                    int m = mbase + j;
                    float v = acc[mi][ni][j];
                    if (MODE == 0) {
                        int b = m >> 11, l = m & 2047;
                        if (ncol < 2048) {
                            int h = ncol >> 7, hd = ncol & 127;
                            qout[((size_t)(b*H_ + h) * L_ + l) * HD_ + hd] = f2bf(v);
                        } else {
                            int cc = ncol - 2048, h = cc >> 7, hd = cc & 127;
                            kout[((size_t)(b*H_ + h) * L_ + l) * HD_ + hd] = f2bf(v);
                        }
                    } else {
                        fout[(size_t)m * N + ncol] = v + bias[ncol];
                    }
                }
            }
        }
    }
}

// ---------------------------------------------------------------- RMSNorm + RoPE
// Q rows additionally scaled by attn-scale * log2(e) for exp2-domain softmax.
__global__ __launch_bounds__(256) void k_normrope(unsigned short* __restrict__ qb,
                                                  unsigned short* __restrict__ kb,
                                                  const float* __restrict__ cosT,
                                                  const float* __restrict__ sinT,
                                                  const float* __restrict__ qw,
                                                  const float* __restrict__ kw) {
    const float QSCL = 0.08838834764831845f * 1.4426950408889634f;  // 1/sqrt(128) * log2(e)
    int lane = threadIdx.x & 63;
    int row = blockIdx.x * 4 + (threadIdx.x >> 6);
    int isK = row >= BH_ * L_;
    unsigned short* buf = isK ? kb : qb;
    const float* w = isK ? kw : qw;
    int r = isK ? row - BH_ * L_ : row;
    int l = r & (L_ - 1);
    unsigned short* p = buf + (size_t)r * HD_ + lane * 2;
    ushort2 u = *(const ushort2*)p;
    float x1 = bf2f(u.x), x2 = bf2f(u.y);
    float ss = x1*x1 + x2*x2;
    #pragma unroll
    for (int off = 32; off; off >>= 1) ss += __shfl_xor(ss, off);
    float rs = rsqrtf(ss * (1.0f / 128.0f) + 1e-6f);
    rs *= isK ? 1.0f : QSCL;
    float c = cosT[l * 64 + lane], s = sinT[l * 64 + lane];
    float y1 = x1 * rs * w[lane * 2];
    float y2 = x2 * rs * w[lane * 2 + 1];
    ushort2 o;
    o.x = f2bf(y1 * c - y2 * s);
    o.y = f2bf(y1 * s + y2 * c);
    *(ushort2*)p = o;
}

// ---------------------------------------------------------------- causal flash attention
// ROUND-9 structure (proven best): 128 q-rows/block, 4 waves, wave owns 32 rows.
// KV tile = 64, K+V staged together, 2 barriers/tile; 3 blocks/CU (50.4KB LDS, 152 VGPR).
// FIXED-BOUND exp2 softmax (P = 2^(S-20)), ones-column MFMA row sums, T5 setprio.
#define PLDT 72

__global__ __launch_bounds__(256) void k_attn(const unsigned short* __restrict__ qbuf,
                                              const unsigned short* __restrict__ kbuf,
                                              const unsigned short* __restrict__ vT,
                                              unsigned short* __restrict__ yb) {
    __shared__ __align__(16) unsigned short Ks[64 * 128];
    __shared__ __align__(16) unsigned short Vs[128 * 64];
    __shared__ __align__(16) unsigned short Ps[4][32 * PLDT];
    int tid = threadIdx.x, lane = tid & 63, w = tid >> 6;
    int l15 = lane & 15, l4 = lane >> 4;
    int qb = 15 - (blockIdx.x >> 6);        // heavy blocks dispatched first
    int bh = blockIdx.x & 63;
    const unsigned short* Q  = qbuf + (size_t)bh * L_ * HD_;
    const unsigned short* Kp = kbuf + (size_t)bh * L_ * HD_;
    const unsigned short* Vp = vT   + (size_t)bh * L_ * HD_;
    int qr0 = qb * 128 + w * 32;

    bf16x8 qf[2][4];
    #pragma unroll
    for (int m = 0; m < 2; ++m)
        #pragma unroll
        for (int ks = 0; ks < 4; ++ks)
            qf[m][ks] = *(const bf16x8*)(Q + (size_t)(qr0 + m*16 + l15) * HD_ + ks*32 + l4*8);

    f32x4 accO[2][8] = {};
    f32x4 accW[2] = {};                      // ones-column row-sum accumulator

    bf16x8 vones;
    #pragma unroll
    for (int i = 0; i < 8; ++i) vones[i] = (__bf16)1.0f;

    const float BOUND = 20.0f;               // fixed softmax reference (log2 domain)
    int nkt = 2 * qb + 2;

    for (int kt = 0; kt < nkt; ++kt) {
        int kbase = kt * 64;
        #pragma unroll
        for (int i = 0; i < 4; ++i) {
            int g = w * 4 + i;
            int kr = g * 4 + (lane >> 4);
            gload16(Kp + (size_t)(kbase + kr) * HD_ + (((lane & 15) ^ (kr & 15)) << 3),
                    Ks + g * 512);
            int vr = g * 8 + (lane >> 3);
            gload16(Vp + (size_t)vr * L_ + kbase + (((lane & 7) ^ (vr & 7)) << 3),
                    Vs + g * 512);
        }
        __syncthreads();

        if (kbase <= qr0 + 31) {   // wave has at least one unmasked row in this tile
            // ---- S = Q K^T (log2 domain)
            f32x4 sf[2][4] = {};
            __builtin_amdgcn_s_setprio(1);
            #pragma unroll
            for (int f = 0; f < 4; ++f)
                #pragma unroll
                for (int ks = 0; ks < 4; ++ks) {
                    bf16x8 kf = *(const bf16x8*)(Ks + (f*16 + l15) * 128 +
                                                 ((((ks*4) + l4) ^ l15) << 3));
                    sf[0][f] = __builtin_amdgcn_mfma_f32_16x16x32_bf16(qf[0][ks], kf, sf[0][f], 0, 0, 0);
                    sf[1][f] = __builtin_amdgcn_mfma_f32_16x16x32_bf16(qf[1][ks], kf, sf[1][f], 0, 0, 0);
                }
            __builtin_amdgcn_s_setprio(0);

            // ---- P = 2^(S - BOUND) with causal mask -> per-wave LDS (A-frag layout)
            unsigned short* ps = Ps[w];
            #pragma unroll
            for (int m = 0; m < 2; ++m) {
                bool needmask = (kbase + 63 > qr0 + m*16);
                #pragma unroll
                for (int f = 0; f < 4; ++f)
                    #pragma unroll
                    for (int j = 0; j < 4; ++j) {
                        float s = sf[m][f][j];
                        if (needmask) {
                            int key  = kbase + f*16 + l15;
                            int qrow = qr0 + m*16 + l4*4 + j;
                            if (key > qrow) s = -1e30f;
                        }
                        float p = exp2f(s - BOUND);
                        *(__bf16*)(ps + (m*16 + l4*4 + j) * PLDT + f*16 + l15) = (__bf16)p;
                    }
            }

            // ---- O += P @ V, row-sum += P @ 1
            __builtin_amdgcn_s_setprio(1);
            #pragma unroll
            for (int ks = 0; ks < 2; ++ks) {
                bf16x8 pa0 = *(const bf16x8*)(ps + l15 * PLDT + ks*32 + l4*8);
                bf16x8 pa1 = *(const bf16x8*)(ps + (16 + l15) * PLDT + ks*32 + l4*8);
                #pragma unroll
                for (int cf = 0; cf < 8; ++cf) {
                    bf16x8 vf = *(const bf16x8*)(Vs + (cf*16 + l15) * 64 +
                                                 ((((ks*4) + l4) ^ (l15 & 7)) << 3));
                    accO[0][cf] = __builtin_amdgcn_mfma_f32_16x16x32_bf16(pa0, vf, accO[0][cf], 0, 0, 0);
                    accO[1][cf] = __builtin_amdgcn_mfma_f32_16x16x32_bf16(pa1, vf, accO[1][cf], 0, 0, 0);
                }
                accW[0] = __builtin_amdgcn_mfma_f32_16x16x32_bf16(pa0, vones, accW[0], 0, 0, 0);
                accW[1] = __builtin_amdgcn_mfma_f32_16x16x32_bf16(pa1, vones, accW[1], 0, 0, 0);
            }
            __builtin_amdgcn_s_setprio(0);
        }
        __syncthreads();
    }

    int b = bh >> 4, h = bh & 15;
    #pragma unroll
    for (int m = 0; m < 2; ++m)
        #pragma unroll
        for (int cf = 0; cf < 8; ++cf)
            #pragma unroll
            for (int j = 0; j < 4; ++j) {
                int qrow = qr0 + m*16 + l4*4 + j;
                float o = accO[m][cf][j] / accW[m][j];
                yb[((size_t)(b * L_ + qrow)) * D_ + h*128 + cf*16 + l15] = f2bf(o);
            }
}

// ---------------------------------------------------------------- launch
extern "C" void kernel_launch(void* const* d_in, const int* in_sizes, int n_in,
                              void* d_out, int out_size, void* d_ws, size_t ws_size,
                              hipStream_t stream) {
    const float* x    = (const float*)d_in[0];
    const float* fcos = (const float*)d_in[1];
    const float* fsin = (const float*)d_in[2];
    const float* Wqk  = (const float*)d_in[3];
    const float* Wv   = (const float*)d_in[4];
    const float* bv   = (const float*)d_in[5];
    const float* Wp   = (const float*)d_in[6];
    const float* bp   = (const float*)d_in[7];
    const float* qn_w = (const float*)d_in[8];
    const float* kn_w = (const float*)d_in[9];
    float* out = (float*)d_out;

    char* ws = (char*)d_ws;
    unsigned short* Wt   = (unsigned short*)(ws);                 // 6144x2048 bf16
    unsigned short* Wpt  = (unsigned short*)(ws + 25165824);      // 2048x2048 bf16
    unsigned short* xb   = (unsigned short*)(ws + 33554432);      // 8192x2048 bf16 (reused as yb)
    unsigned short* qbuf = (unsigned short*)(ws + 67108864);      // (BH,L,HD) bf16
    unsigned short* kbuf = (unsigned short*)(ws + 100663296);
    unsigned short* vTb  = (unsigned short*)(ws + 167772160);     // (BH,HD,L) bf16 (written directly by gemm<0>)
    unsigned short* yb   = xb;

    k_f32_to_bf16<<<8192, 256, 0, stream>>>(x, xb, BL_ * D_ / 8);
    k_transpose_f2b<<<dim3(128, 64), 256, 0, stream>>>(Wqk, Wt, 2048, 4096, 2048);
    k_transpose_f2b<<<dim3(64, 64),  256, 0, stream>>>(Wv,  Wt + (size_t)4096 * 2048, 2048, 2048, 2048);
    k_transpose_f2b<<<dim3(64, 64),  256, 0, stream>>>(Wp,  Wpt, 2048, 2048, 2048);

    k_gemm<0><<<dim3(48, 64), 256, 0, stream>>>(xb, Wt, BL_, 6144, 2048, bv,
                                                qbuf, kbuf, vTb, nullptr);
    k_normrope<<<2 * BH_ * L_ / 4, 256, 0, stream>>>(qbuf, kbuf, fcos, fsin, qn_w, kn_w);
    k_attn<<<BH_ * (L_ / 128), 256, 0, stream>>>(qbuf, kbuf, vTb, yb);
    k_gemm<1><<<dim3(16, 64), 256, 0, stream>>>(yb, Wpt, BL_, 2048, 2048, bp,
                                                nullptr, nullptr, nullptr, out);
}

// Round 14
// 453.390 us; speedup vs baseline: 1.1317x; 1.1317x over previous
//
#include <hip/hip_runtime.h>
#include <hip/hip_bf16.h>
#include <math.h>

// Problem constants
#define B_  4
#define L_  2048
#define D_  2048
#define H_  16
#define HD_ 128
#define BH_ (B_*H_)   // 64
#define BL_ (B_*L_)   // 8192

typedef __attribute__((ext_vector_type(4))) float  f32x4;
typedef __attribute__((ext_vector_type(8))) __bf16 bf16x8;

static __device__ __forceinline__ float bf2f(unsigned short u) {
    union { unsigned int i; float f; } v; v.i = ((unsigned int)u) << 16; return v.f;
}
static __device__ __forceinline__ unsigned short f2bf(float f) {
    union { float f; unsigned int i; } v; v.f = f;
    unsigned int x = v.i;
    return (unsigned short)((x + 0x7fffu + ((x >> 16) & 1u)) >> 16);  // RNE
}

// async global->LDS, 16B per lane. lds base must be wave-uniform; HW scatters +lane*16B.
static __device__ __forceinline__ void gload16(const unsigned short* g, unsigned short* l) {
    __builtin_amdgcn_global_load_lds(
        (const __attribute__((address_space(1))) unsigned int*)(const void*)g,
        (__attribute__((address_space(3))) unsigned int*)(void*)l, 16, 0, 0);
}

// ---------------------------------------------------------------- convert x -> bf16
__global__ __launch_bounds__(256) void k_f32_to_bf16(const float* __restrict__ s,
                                                     unsigned short* __restrict__ d, int n8) {
    int i = blockIdx.x * 256 + threadIdx.x;
    if (i >= n8) return;
    const float* p = s + (size_t)i * 8;
    float4 a = *(const float4*)p;
    float4 b = *(const float4*)(p + 4);
    union { bf16x8 v; unsigned short u[8]; } o;
    o.u[0]=f2bf(a.x); o.u[1]=f2bf(a.y); o.u[2]=f2bf(a.z); o.u[3]=f2bf(a.w);
    o.u[4]=f2bf(b.x); o.u[5]=f2bf(b.y); o.u[6]=f2bf(b.z); o.u[7]=f2bf(b.w);
    *(bf16x8*)(d + (size_t)i * 8) = o.v;
}

// ---------------------------------------------------------------- transpose f32 -> bf16
__global__ __launch_bounds__(256) void k_transpose_f2b(const float* __restrict__ src,
                                                       unsigned short* __restrict__ dst,
                                                       int R, int C, int dstStride) {
    __shared__ float tile[32][33];
    int tx = threadIdx.x & 31, ty = threadIdx.x >> 5;   // 32 x 8
    int c0 = blockIdx.x * 32, r0 = blockIdx.y * 32;
    #pragma unroll
    for (int i = 0; i < 32; i += 8)
        tile[ty + i][tx] = src[(size_t)(r0 + ty + i) * C + c0 + tx];
    __syncthreads();
    #pragma unroll
    for (int i = 0; i < 32; i += 8)
        dst[(size_t)(c0 + ty + i) * dstStride + r0 + tx] = f2bf(tile[tx][ty + i]);
}

// ---------------------------------------------------------------- 256x256 GEMM, counted-lgkm pipeline
// 512 thr / 8 waves (2M x 4N), BK=64, 128 KiB LDS = 2dbuf x {A-unit(mg), B-unit(ng)} x 16KB.
// 3 phases / 4 barriers per K-tile; counted lgkm waits overlap ds-drains with MFMA.
// vmcnt(6) at ph3: drains exactly A1(t+1); leaves all of tile t+2 in flight.
// In-flight invariant at tile end: {A0,B0,B1}(t+2) = 6. Prologue t0(8)+t1(6), vmcnt(6)
// drains t0. WAR gates: A0-stage after b2; B0/B1-stage after b4; A1-stage after prior b5.
// XOR slot swizzle on SOURCE addr and READ (linear gload_lds dest) -- rule 21.

template<int MG, int NG>
static __device__ __forceinline__ void mfma_quad(const bf16x8 (&afr)[4][2],
                                                 const bf16x8 (&bfr)[2][2],
                                                 f32x4 (&acc)[8][4]) {
    #pragma unroll
    for (int mi = 0; mi < 4; ++mi)
        #pragma unroll
        for (int ni = 0; ni < 2; ++ni) {
            acc[MG*4+mi][NG*2+ni] = __builtin_amdgcn_mfma_f32_16x16x32_bf16(
                afr[mi][0], bfr[ni][0], acc[MG*4+mi][NG*2+ni], 0, 0, 0);
            acc[MG*4+mi][NG*2+ni] = __builtin_amdgcn_mfma_f32_16x16x32_bf16(
                afr[mi][1], bfr[ni][1], acc[MG*4+mi][NG*2+ni], 0, 0, 0);
        }
}

static __device__ __forceinline__ void ds_load_a(const unsigned short* u, int wm,
                                                 int l15, int l4, bf16x8 (&afr)[4][2]) {
    int sw = l15 & 7;
    #pragma unroll
    for (int mi = 0; mi < 4; ++mi) {
        int ro = (wm*64 + mi*16 + l15) * 64;
        afr[mi][0] = *(const bf16x8*)(u + ro + ((l4 ^ sw) << 3));
        afr[mi][1] = *(const bf16x8*)(u + ro + (((4 + l4) ^ sw) << 3));
    }
}

static __device__ __forceinline__ void ds_load_b(const unsigned short* u, int wn,
                                                 int l15, int l4, bf16x8 (&bfr)[2][2]) {
    int sw = l15 & 7;
    #pragma unroll
    for (int ni = 0; ni < 2; ++ni) {
        int ro = (wn*32 + ni*16 + l15) * 64;
        bfr[ni][0] = *(const bf16x8*)(u + ro + ((l4 ^ sw) << 3));
        bfr[ni][1] = *(const bf16x8*)(u + ro + (((4 + l4) ^ sw) << 3));
    }
}

#define STAGE_A_(c_, mg_, t_) do {                                                        \
    gload16(gA + (size_t)(((mg_)*64      ) * 2048) + (t_)*64, &Lds[c_][0][mg_][w*512]);   \
    gload16(gA + (size_t)(((mg_)*64 + 128) * 2048) + (t_)*64, &Lds[c_][0][mg_][4096 + w*512]); \
} while (0)
#define STAGE_B_(c_, ng_, t_) do {                                                        \
    gload16(gB + (size_t)(((ng_)*32 + ((w>>2)    )*64) * 2048) + (t_)*64, &Lds[c_][1][ng_][w*512]); \
    gload16(gB + (size_t)(((ng_)*32 + ((w>>2) + 2)*64) * 2048) + (t_)*64, &Lds[c_][1][ng_][4096 + w*512]); \
} while (0)
#define SB_() __builtin_amdgcn_sched_barrier(0)

template<int MODE>
__global__ __launch_bounds__(512, 2) void k_gemm(const unsigned short* __restrict__ A,
                                                 const unsigned short* __restrict__ Bt,
                                                 int M, int N, int K,
                                                 const float* __restrict__ bias,
                                                 unsigned short* __restrict__ qout,
                                                 unsigned short* __restrict__ kout,
                                                 unsigned short* __restrict__ vout,
                                                 float* __restrict__ fout) {
    (void)K;
    __shared__ __align__(16) unsigned short Lds[2][2][2][8192];  // [dbuf][A/B][unit][16KB]
    const int tid = threadIdx.x;
    const int lane = tid & 63, w = tid >> 6;      // 8 waves
    const int wm = w >> 2, wn = w & 3;            // 2M x 4N
    const int l15 = lane & 15, l4 = lane >> 4;
    const int lsw = (lane & 7) ^ ((lane >> 3) & 7);

    int nwgx = gridDim.x;
    int bid = blockIdx.y * nwgx + blockIdx.x;
    int cpx = (nwgx * gridDim.y) >> 3;
    int sb = (bid & 7) * cpx + (bid >> 3);
    int n0 = (sb % nwgx) * 256, m0 = (sb / nwgx) * 256;

    const unsigned short* gA = A  + (size_t)(m0 + w*8 + (lane >> 3)) * 2048 + lsw*8;
    const unsigned short* gB = Bt + (size_t)(n0 + (w&3)*8 + (lane >> 3)) * 2048 + lsw*8;

    f32x4 acc[8][4] = {};
    bf16x8 afr[4][2], bf0[2][2], bf1[2][2];
    const int nt = 2048 / 64;  // 32 K-tiles

    STAGE_A_(0, 0, 0); STAGE_B_(0, 0, 0); STAGE_B_(0, 1, 0); STAGE_A_(0, 1, 0);
    STAGE_A_(1, 0, 1); STAGE_B_(1, 0, 1); STAGE_B_(1, 1, 1);
    asm volatile("s_waitcnt vmcnt(6)" ::: "memory");
    __builtin_amdgcn_s_barrier();

    for (int t = 0; t < nt; ++t) {
        const int c = t & 1, cn = c ^ 1;
        const bool h1 = (t + 1 < nt), h2 = (t + 2 < nt);

        ds_load_a(&Lds[c][0][0][0], wm, l15, l4, afr);
        ds_load_b(&Lds[c][1][0][0], wn, l15, l4, bf0);
        SB_();
        ds_load_b(&Lds[c][1][1][0], wn, l15, l4, bf1);
        SB_();
        if (h1) STAGE_A_(cn, 1, t + 1);
        __builtin_amdgcn_s_barrier();                       // b1
        asm volatile("s_waitcnt lgkmcnt(4)" ::: "memory");  // A0,B0 landed; B1 in flight
        SB_();
        __builtin_amdgcn_s_setprio(1);
        mfma_quad<0, 0>(afr, bf0, acc);
        __builtin_amdgcn_s_setprio(0);
        SB_();
        __builtin_amdgcn_s_barrier();                       // b2

        asm volatile("s_waitcnt lgkmcnt(0)" ::: "memory");  // B1 landed
        SB_();
        __builtin_amdgcn_s_setprio(1);
        mfma_quad<0, 1>(afr, bf1, acc);
        __builtin_amdgcn_s_setprio(0);
        SB_();
        ds_load_a(&Lds[c][0][1][0], wm, l15, l4, afr);      // A1 -> afr
        SB_();
        if (h2) STAGE_A_(c, 0, t + 2);
        __builtin_amdgcn_s_barrier();                       // b4

        if (h2) STAGE_B_(c, 0, t + 2);
        asm volatile("s_waitcnt lgkmcnt(0)" ::: "memory");  // A1 landed
        SB_();
        __builtin_amdgcn_s_setprio(1);
        mfma_quad<1, 1>(afr, bf1, acc);
        __builtin_amdgcn_s_setprio(0);
        SB_();
        if (h2) STAGE_B_(c, 1, t + 2);
        __builtin_amdgcn_s_setprio(1);
        mfma_quad<1, 0>(afr, bf0, acc);
        __builtin_amdgcn_s_setprio(0);
        SB_();
        if (h2) asm volatile("s_waitcnt vmcnt(6)" ::: "memory");
        else    asm volatile("s_waitcnt vmcnt(0)" ::: "memory");
        __builtin_amdgcn_s_barrier();                       // b5
    }

    // ---- epilogue; MODE 0 writes V TRANSPOSED (BH,HD,L) directly (8B packed j-quad)
    #pragma unroll
    for (int mi = 0; mi < 8; ++mi) {
        #pragma unroll
        for (int ni = 0; ni < 4; ++ni) {
            int ncol = n0 + wn*64 + ni*16 + l15;
            int mbase = m0 + wm*128 + mi*16 + l4*4;
            if (MODE == 0 && ncol >= 4096) {
                int cc = ncol - 4096, h = cc >> 7, hd = cc & 127;
                int b = mbase >> 11, l = mbase & 2047;   // 4 consecutive l, same b
                float bv = bias[cc];
                ushort4 o;
                o.x = f2bf(acc[mi][ni][0] + bv);
                o.y = f2bf(acc[mi][ni][1] + bv);
                o.z = f2bf(acc[mi][ni][2] + bv);
                o.w = f2bf(acc[mi][ni][3] + bv);
                *(ushort4*)(vout + ((size_t)((b*H_ + h) * HD_ + hd)) * L_ + l) = o;
            } else {
                #pragma unroll
                for (int j = 0; j < 4; ++j) {
                    int m = mbase + j;
                    float v = acc[mi][ni][j];
                    if (MODE == 0) {
                        int b = m >> 11, l = m & 2047;
                        if (ncol < 2048) {
                            int h = ncol >> 7, hd = ncol & 127;
                            qout[((size_t)(b*H_ + h) * L_ + l) * HD_ + hd] = f2bf(v);
                        } else {
                            int cc = ncol - 2048, h = cc >> 7, hd = cc & 127;
                            kout[((size_t)(b*H_ + h) * L_ + l) * HD_ + hd] = f2bf(v);
                        }
                    } else {
                        fout[(size_t)m * N + ncol] = v + bias[ncol];
                    }
                }
            }
        }
    }
}

// ---------------------------------------------------------------- RMSNorm + RoPE
// Q rows additionally scaled by attn-scale * log2(e) for exp2-domain softmax.
__global__ __launch_bounds__(256) void k_normrope(unsigned short* __restrict__ qb,
                                                  unsigned short* __restrict__ kb,
                                                  const float* __restrict__ cosT,
                                                  const float* __restrict__ sinT,
                                                  const float* __restrict__ qw,
                                                  const float* __restrict__ kw) {
    const float QSCL = 0.08838834764831845f * 1.4426950408889634f;  // 1/sqrt(128) * log2(e)
    int lane = threadIdx.x & 63;
    int row = blockIdx.x * 4 + (threadIdx.x >> 6);
    int isK = row >= BH_ * L_;
    unsigned short* buf = isK ? kb : qb;
    const float* w = isK ? kw : qw;
    int r = isK ? row - BH_ * L_ : row;
    int l = r & (L_ - 1);
    unsigned short* p = buf + (size_t)r * HD_ + lane * 2;
    ushort2 u = *(const ushort2*)p;
    float x1 = bf2f(u.x), x2 = bf2f(u.y);
    float ss = x1*x1 + x2*x2;
    #pragma unroll
    for (int off = 32; off; off >>= 1) ss += __shfl_xor(ss, off);
    float rs = rsqrtf(ss * (1.0f / 128.0f) + 1e-6f);
    rs *= isK ? 1.0f : QSCL;
    float c = cosT[l * 64 + lane], s = sinT[l * 64 + lane];
    float y1 = x1 * rs * w[lane * 2];
    float y2 = x2 * rs * w[lane * 2 + 1];
    ushort2 o;
    o.x = f2bf(y1 * c - y2 * s);
    o.y = f2bf(y1 * s + y2 * c);
    *(ushort2*)p = o;
}

// ---------------------------------------------------------------- causal flash attention
// 128 q-rows/block, 4 waves, wave owns 32 rows. KV tile = 64; K+V staged together,
// 2 barriers/tile; 3 blocks/CU (50KB LDS, 152 VGPR). FIXED-BOUND exp2 softmax
// (P = 2^(S-20), no max/rescale). Ones-column MFMA row sums. T5 setprio.
#define PLDT 72

__global__ __launch_bounds__(256) void k_attn(const unsigned short* __restrict__ qbuf,
                                              const unsigned short* __restrict__ kbuf,
                                              const unsigned short* __restrict__ vT,
                                              unsigned short* __restrict__ yb) {
    __shared__ __align__(16) unsigned short Ks[64 * 128];
    __shared__ __align__(16) unsigned short Vs[128 * 64];
    __shared__ __align__(16) unsigned short Ps[4][32 * PLDT];
    int tid = threadIdx.x, lane = tid & 63, w = tid >> 6;
    int l15 = lane & 15, l4 = lane >> 4;
    int qb = 15 - (blockIdx.x >> 6);        // heavy blocks dispatched first
    int bh = blockIdx.x & 63;
    const unsigned short* Q  = qbuf + (size_t)bh * L_ * HD_;
    const unsigned short* Kp = kbuf + (size_t)bh * L_ * HD_;
    const unsigned short* Vp = vT   + (size_t)bh * L_ * HD_;
    int qr0 = qb * 128 + w * 32;

    bf16x8 qf[2][4];
    #pragma unroll
    for (int m = 0; m < 2; ++m)
        #pragma unroll
        for (int ks = 0; ks < 4; ++ks)
            qf[m][ks] = *(const bf16x8*)(Q + (size_t)(qr0 + m*16 + l15) * HD_ + ks*32 + l4*8);

    f32x4 accO[2][8] = {};
    f32x4 accW[2] = {};                      // ones-column row-sum accumulator

    bf16x8 vones;
    #pragma unroll
    for (int i = 0; i < 8; ++i) vones[i] = (__bf16)1.0f;

    const float BOUND = 20.0f;               // fixed softmax reference (log2 domain)
    int nkt = 2 * qb + 2;

    for (int kt = 0; kt < nkt; ++kt) {
        int kbase = kt * 64;
        #pragma unroll
        for (int i = 0; i < 4; ++i) {
            int g = w * 4 + i;
            int kr = g * 4 + (lane >> 4);
            gload16(Kp + (size_t)(kbase + kr) * HD_ + (((lane & 15) ^ (kr & 15)) << 3),
                    Ks + g * 512);
            int vr = g * 8 + (lane >> 3);
            gload16(Vp + (size_t)vr * L_ + kbase + (((lane & 7) ^ (vr & 7)) << 3),
                    Vs + g * 512);
        }
        __syncthreads();

        if (kbase <= qr0 + 31) {   // wave has at least one unmasked row in this tile
            // ---- S = Q K^T (log2 domain)
            f32x4 sf[2][4] = {};
            __builtin_amdgcn_s_setprio(1);
            #pragma unroll
            for (int f = 0; f < 4; ++f)
                #pragma unroll
                for (int ks = 0; ks < 4; ++ks) {
                    bf16x8 kf = *(const bf16x8*)(Ks + (f*16 + l15) * 128 +
                                                 ((((ks*4) + l4) ^ l15) << 3));
                    sf[0][f] = __builtin_amdgcn_mfma_f32_16x16x32_bf16(qf[0][ks], kf, sf[0][f], 0, 0, 0);
                    sf[1][f] = __builtin_amdgcn_mfma_f32_16x16x32_bf16(qf[1][ks], kf, sf[1][f], 0, 0, 0);
                }
            __builtin_amdgcn_s_setprio(0);

            // ---- P = 2^(S - BOUND) with causal mask -> per-wave LDS (A-frag layout)
            unsigned short* ps = Ps[w];
            #pragma unroll
            for (int m = 0; m < 2; ++m) {
                bool needmask = (kbase + 63 > qr0 + m*16);
                #pragma unroll
                for (int f = 0; f < 4; ++f)
                    #pragma unroll
                    for (int j = 0; j < 4; ++j) {
                        float s = sf[m][f][j];
                        if (needmask) {
                            int key  = kbase + f*16 + l15;
                            int qrow = qr0 + m*16 + l4*4 + j;
                            if (key > qrow) s = -1e30f;
                        }
                        float p = exp2f(s - BOUND);
                        *(__bf16*)(ps + (m*16 + l4*4 + j) * PLDT + f*16 + l15) = (__bf16)p;
                    }
            }

            // ---- O += P @ V, row-sum += P @ 1
            __builtin_amdgcn_s_setprio(1);
            #pragma unroll
            for (int ks = 0; ks < 2; ++ks) {
                bf16x8 pa0 = *(const bf16x8*)(ps + l15 * PLDT + ks*32 + l4*8);
                bf16x8 pa1 = *(const bf16x8*)(ps + (16 + l15) * PLDT + ks*32 + l4*8);
                #pragma unroll
                for (int cf = 0; cf < 8; ++cf) {
                    bf16x8 vf = *(const bf16x8*)(Vs + (cf*16 + l15) * 64 +
                                                 ((((ks*4) + l4) ^ (l15 & 7)) << 3));
                    accO[0][cf] = __builtin_amdgcn_mfma_f32_16x16x32_bf16(pa0, vf, accO[0][cf], 0, 0, 0);
                    accO[1][cf] = __builtin_amdgcn_mfma_f32_16x16x32_bf16(pa1, vf, accO[1][cf], 0, 0, 0);
                }
                accW[0] = __builtin_amdgcn_mfma_f32_16x16x32_bf16(pa0, vones, accW[0], 0, 0, 0);
                accW[1] = __builtin_amdgcn_mfma_f32_16x16x32_bf16(pa1, vones, accW[1], 0, 0, 0);
            }
            __builtin_amdgcn_s_setprio(0);
        }
        __syncthreads();
    }

    int b = bh >> 4, h = bh & 15;
    #pragma unroll
    for (int m = 0; m < 2; ++m)
        #pragma unroll
        for (int cf = 0; cf < 8; ++cf)
            #pragma unroll
            for (int j = 0; j < 4; ++j) {
                int qrow = qr0 + m*16 + l4*4 + j;
                float o = accO[m][cf][j] / accW[m][j];
                yb[((size_t)(b * L_ + qrow)) * D_ + h*128 + cf*16 + l15] = f2bf(o);
            }
}

// ---------------------------------------------------------------- launch
extern "C" void kernel_launch(void* const* d_in, const int* in_sizes, int n_in,
                              void* d_out, int out_size, void* d_ws, size_t ws_size,
                              hipStream_t stream) {
    const float* x    = (const float*)d_in[0];
    const float* fcos = (const float*)d_in[1];
    const float* fsin = (const float*)d_in[2];
    const float* Wqk  = (const float*)d_in[3];
    const float* Wv   = (const float*)d_in[4];
    const float* bv   = (const float*)d_in[5];
    const float* Wp   = (const float*)d_in[6];
    const float* bp   = (const float*)d_in[7];
    const float* qn_w = (const float*)d_in[8];
    const float* kn_w = (const float*)d_in[9];
    float* out = (float*)d_out;

    char* ws = (char*)d_ws;
    unsigned short* Wt   = (unsigned short*)(ws);                 // 6144x2048 bf16
    unsigned short* Wpt  = (unsigned short*)(ws + 25165824);      // 2048x2048 bf16
    unsigned short* xb   = (unsigned short*)(ws + 33554432);      // 8192x2048 bf16 (reused as yb)
    unsigned short* qbuf = (unsigned short*)(ws + 67108864);      // (BH,L,HD) bf16
    unsigned short* kbuf = (unsigned short*)(ws + 100663296);
    unsigned short* vTb  = (unsigned short*)(ws + 167772160);     // (BH,HD,L) bf16 (written directly by gemm<0>)
    unsigned short* yb   = xb;

    k_f32_to_bf16<<<8192, 256, 0, stream>>>(x, xb, BL_ * D_ / 8);
    k_transpose_f2b<<<dim3(128, 64), 256, 0, stream>>>(Wqk, Wt, 2048, 4096, 2048);
    k_transpose_f2b<<<dim3(64, 64),  256, 0, stream>>>(Wv,  Wt + (size_t)4096 * 2048, 2048, 2048, 2048);
    k_transpose_f2b<<<dim3(64, 64),  256, 0, stream>>>(Wp,  Wpt, 2048, 2048, 2048);

    k_gemm<0><<<dim3(24, 32), 512, 0, stream>>>(xb, Wt, BL_, 6144, 2048, bv,
                                                qbuf, kbuf, vTb, nullptr);
    k_normrope<<<2 * BH_ * L_ / 4, 256, 0, stream>>>(qbuf, kbuf, fcos, fsin, qn_w, kn_w);
    k_attn<<<BH_ * (L_ / 128), 256, 0, stream>>>(qbuf, kbuf, vTb, yb);
    k_gemm<1><<<dim3(8, 32), 512, 0, stream>>>(yb, Wpt, BL_, 2048, 2048, bp,
                                               nullptr, nullptr, nullptr, out);
}

// Round 15
// 450.405 us; speedup vs baseline: 1.1392x; 1.0066x over previous
//
#include <hip/hip_runtime.h>
#include <hip/hip_bf16.h>
#include <math.h>

// Problem constants
#define B_  4
#define L_  2048
#define D_  2048
#define H_  16
#define HD_ 128
#define BH_ (B_*H_)   // 64
#define BL_ (B_*L_)   // 8192

typedef __attribute__((ext_vector_type(4))) float  f32x4;
typedef __attribute__((ext_vector_type(8))) __bf16 bf16x8;

static __device__ __forceinline__ float bf2f(unsigned short u) {
    union { unsigned int i; float f; } v; v.i = ((unsigned int)u) << 16; return v.f;
}
static __device__ __forceinline__ unsigned short f2bf(float f) {
    union { float f; unsigned int i; } v; v.f = f;
    unsigned int x = v.i;
    return (unsigned short)((x + 0x7fffu + ((x >> 16) & 1u)) >> 16);  // RNE
}

// async global->LDS, 16B per lane. lds base must be wave-uniform; HW scatters +lane*16B.
static __device__ __forceinline__ void gload16(const unsigned short* g, unsigned short* l) {
    __builtin_amdgcn_global_load_lds(
        (const __attribute__((address_space(1))) unsigned int*)(const void*)g,
        (__attribute__((address_space(3))) unsigned int*)(void*)l, 16, 0, 0);
}

// ---------------------------------------------------------------- convert x -> bf16
__global__ __launch_bounds__(256) void k_f32_to_bf16(const float* __restrict__ s,
                                                     unsigned short* __restrict__ d, int n8) {
    int i = blockIdx.x * 256 + threadIdx.x;
    if (i >= n8) return;
    const float* p = s + (size_t)i * 8;
    float4 a = *(const float4*)p;
    float4 b = *(const float4*)(p + 4);
    union { bf16x8 v; unsigned short u[8]; } o;
    o.u[0]=f2bf(a.x); o.u[1]=f2bf(a.y); o.u[2]=f2bf(a.z); o.u[3]=f2bf(a.w);
    o.u[4]=f2bf(b.x); o.u[5]=f2bf(b.y); o.u[6]=f2bf(b.z); o.u[7]=f2bf(b.w);
    *(bf16x8*)(d + (size_t)i * 8) = o.v;
}

// ---------------------------------------------------------------- transpose f32 -> bf16
__global__ __launch_bounds__(256) void k_transpose_f2b(const float* __restrict__ src,
                                                       unsigned short* __restrict__ dst,
                                                       int R, int C, int dstStride) {
    __shared__ float tile[32][33];
    int tx = threadIdx.x & 31, ty = threadIdx.x >> 5;   // 32 x 8
    int c0 = blockIdx.x * 32, r0 = blockIdx.y * 32;
    #pragma unroll
    for (int i = 0; i < 32; i += 8)
        tile[ty + i][tx] = src[(size_t)(r0 + ty + i) * C + c0 + tx];
    __syncthreads();
    #pragma unroll
    for (int i = 0; i < 32; i += 8)
        dst[(size_t)(c0 + ty + i) * dstStride + r0 + tx] = f2bf(tile[tx][ty + i]);
}

// ---------------------------------------------------------------- 256x256 GEMM, counted-lgkm pipeline
// 512 thr / 8 waves (2M x 4N), BK=64, 128 KiB LDS = 2dbuf x {A-unit(mg), B-unit(ng)} x 16KB.
// 3 phases / 4 barriers per K-tile; counted lgkm waits overlap ds-drains with MFMA.
// vmcnt(6) at ph3: drains exactly A1(t+1); leaves all of tile t+2 in flight.
// K-loop UNROLLED x2 (nt=32 even): dbuf index c becomes compile-time per copy ->
// LDS offsets fold to immediates, staging bases loop-invariant (address-VALU cut).
// WAR gates: A0-stage after b2; B0/B1-stage after b4; A1-stage after prior b5.
// XOR slot swizzle on SOURCE addr and READ (linear gload_lds dest) -- rule 21.

template<int MG, int NG>
static __device__ __forceinline__ void mfma_quad(const bf16x8 (&afr)[4][2],
                                                 const bf16x8 (&bfr)[2][2],
                                                 f32x4 (&acc)[8][4]) {
    #pragma unroll
    for (int mi = 0; mi < 4; ++mi)
        #pragma unroll
        for (int ni = 0; ni < 2; ++ni) {
            acc[MG*4+mi][NG*2+ni] = __builtin_amdgcn_mfma_f32_16x16x32_bf16(
                afr[mi][0], bfr[ni][0], acc[MG*4+mi][NG*2+ni], 0, 0, 0);
            acc[MG*4+mi][NG*2+ni] = __builtin_amdgcn_mfma_f32_16x16x32_bf16(
                afr[mi][1], bfr[ni][1], acc[MG*4+mi][NG*2+ni], 0, 0, 0);
        }
}

static __device__ __forceinline__ void ds_load_a(const unsigned short* u, int wm,
                                                 int l15, int l4, bf16x8 (&afr)[4][2]) {
    int sw = l15 & 7;
    #pragma unroll
    for (int mi = 0; mi < 4; ++mi) {
        int ro = (wm*64 + mi*16 + l15) * 64;
        afr[mi][0] = *(const bf16x8*)(u + ro + ((l4 ^ sw) << 3));
        afr[mi][1] = *(const bf16x8*)(u + ro + (((4 + l4) ^ sw) << 3));
    }
}

static __device__ __forceinline__ void ds_load_b(const unsigned short* u, int wn,
                                                 int l15, int l4, bf16x8 (&bfr)[2][2]) {
    int sw = l15 & 7;
    #pragma unroll
    for (int ni = 0; ni < 2; ++ni) {
        int ro = (wn*32 + ni*16 + l15) * 64;
        bfr[ni][0] = *(const bf16x8*)(u + ro + ((l4 ^ sw) << 3));
        bfr[ni][1] = *(const bf16x8*)(u + ro + (((4 + l4) ^ sw) << 3));
    }
}

#define STAGE_A_(c_, mg_, t_) do {                                                        \
    gload16(gA + (size_t)(((mg_)*64      ) * 2048) + (t_)*64, &Lds[c_][0][mg_][w*512]);   \
    gload16(gA + (size_t)(((mg_)*64 + 128) * 2048) + (t_)*64, &Lds[c_][0][mg_][4096 + w*512]); \
} while (0)
#define STAGE_B_(c_, ng_, t_) do {                                                        \
    gload16(gB + (size_t)(((ng_)*32 + ((w>>2)    )*64) * 2048) + (t_)*64, &Lds[c_][1][ng_][w*512]); \
    gload16(gB + (size_t)(((ng_)*32 + ((w>>2) + 2)*64) * 2048) + (t_)*64, &Lds[c_][1][ng_][4096 + w*512]); \
} while (0)
#define SB_() __builtin_amdgcn_sched_barrier(0)

// one K-tile body with compile-time dbuf index C_ (CN_ = C_^1)
#define KTILE_BODY_(C_, CN_, t_) do {                                                     \
    const bool h1 = ((t_) + 1 < nt), h2 = ((t_) + 2 < nt);                                \
    ds_load_a(&Lds[C_][0][0][0], wm, l15, l4, afr);                                       \
    ds_load_b(&Lds[C_][1][0][0], wn, l15, l4, bf0);                                       \
    SB_();                                                                                \
    ds_load_b(&Lds[C_][1][1][0], wn, l15, l4, bf1);                                       \
    SB_();                                                                                \
    if (h1) STAGE_A_(CN_, 1, (t_) + 1);                                                   \
    __builtin_amdgcn_s_barrier();                       /* b1 */                          \
    asm volatile("s_waitcnt lgkmcnt(4)" ::: "memory");  /* A0,B0 landed */                \
    SB_();                                                                                \
    __builtin_amdgcn_s_setprio(1);                                                        \
    mfma_quad<0, 0>(afr, bf0, acc);                                                       \
    __builtin_amdgcn_s_setprio(0);                                                        \
    SB_();                                                                                \
    __builtin_amdgcn_s_barrier();                       /* b2 */                          \
    asm volatile("s_waitcnt lgkmcnt(0)" ::: "memory");  /* B1 landed */                   \
    SB_();                                                                                \
    __builtin_amdgcn_s_setprio(1);                                                        \
    mfma_quad<0, 1>(afr, bf1, acc);                                                       \
    __builtin_amdgcn_s_setprio(0);                                                        \
    SB_();                                                                                \
    ds_load_a(&Lds[C_][0][1][0], wm, l15, l4, afr);     /* A1 -> afr */                   \
    SB_();                                                                                \
    if (h2) STAGE_A_(C_, 0, (t_) + 2);                                                    \
    __builtin_amdgcn_s_barrier();                       /* b4 */                          \
    if (h2) STAGE_B_(C_, 0, (t_) + 2);                                                    \
    asm volatile("s_waitcnt lgkmcnt(0)" ::: "memory");  /* A1 landed */                   \
    SB_();                                                                                \
    __builtin_amdgcn_s_setprio(1);                                                        \
    mfma_quad<1, 1>(afr, bf1, acc);                                                       \
    __builtin_amdgcn_s_setprio(0);                                                        \
    SB_();                                                                                \
    if (h2) STAGE_B_(C_, 1, (t_) + 2);                                                    \
    __builtin_amdgcn_s_setprio(1);                                                        \
    mfma_quad<1, 0>(afr, bf0, acc);                                                       \
    __builtin_amdgcn_s_setprio(0);                                                        \
    SB_();                                                                                \
    if (h2) asm volatile("s_waitcnt vmcnt(6)" ::: "memory");                              \
    else    asm volatile("s_waitcnt vmcnt(0)" ::: "memory");                              \
    __builtin_amdgcn_s_barrier();                       /* b5 */                          \
} while (0)

template<int MODE>
__global__ __launch_bounds__(512, 2) void k_gemm(const unsigned short* __restrict__ A,
                                                 const unsigned short* __restrict__ Bt,
                                                 int M, int N, int K,
                                                 const float* __restrict__ bias,
                                                 unsigned short* __restrict__ qout,
                                                 unsigned short* __restrict__ kout,
                                                 unsigned short* __restrict__ vout,
                                                 float* __restrict__ fout) {
    (void)K;
    __shared__ __align__(16) unsigned short Lds[2][2][2][8192];  // [dbuf][A/B][unit][16KB]
    const int tid = threadIdx.x;
    const int lane = tid & 63, w = tid >> 6;      // 8 waves
    const int wm = w >> 2, wn = w & 3;            // 2M x 4N
    const int l15 = lane & 15, l4 = lane >> 4;
    const int lsw = (lane & 7) ^ ((lane >> 3) & 7);

    int nwgx = gridDim.x;
    int bid = blockIdx.y * nwgx + blockIdx.x;
    int cpx = (nwgx * gridDim.y) >> 3;
    int sb = (bid & 7) * cpx + (bid >> 3);
    int n0 = (sb % nwgx) * 256, m0 = (sb / nwgx) * 256;

    const unsigned short* gA = A  + (size_t)(m0 + w*8 + (lane >> 3)) * 2048 + lsw*8;
    const unsigned short* gB = Bt + (size_t)(n0 + (w&3)*8 + (lane >> 3)) * 2048 + lsw*8;

    f32x4 acc[8][4] = {};
    bf16x8 afr[4][2], bf0[2][2], bf1[2][2];
    const int nt = 2048 / 64;  // 32 K-tiles (even -> clean x2 unroll)

    STAGE_A_(0, 0, 0); STAGE_B_(0, 0, 0); STAGE_B_(0, 1, 0); STAGE_A_(0, 1, 0);
    STAGE_A_(1, 0, 1); STAGE_B_(1, 0, 1); STAGE_B_(1, 1, 1);
    asm volatile("s_waitcnt vmcnt(6)" ::: "memory");
    __builtin_amdgcn_s_barrier();

    for (int t = 0; t < nt; t += 2) {
        KTILE_BODY_(0, 1, t);
        KTILE_BODY_(1, 0, t + 1);
    }

    // ---- epilogue; MODE 0 writes V TRANSPOSED (BH,HD,L) directly (8B packed j-quad)
    #pragma unroll
    for (int mi = 0; mi < 8; ++mi) {
        #pragma unroll
        for (int ni = 0; ni < 4; ++ni) {
            int ncol = n0 + wn*64 + ni*16 + l15;
            int mbase = m0 + wm*128 + mi*16 + l4*4;
            if (MODE == 0 && ncol >= 4096) {
                int cc = ncol - 4096, h = cc >> 7, hd = cc & 127;
                int b = mbase >> 11, l = mbase & 2047;   // 4 consecutive l, same b
                float bv = bias[cc];
                ushort4 o;
                o.x = f2bf(acc[mi][ni][0] + bv);
                o.y = f2bf(acc[mi][ni][1] + bv);
                o.z = f2bf(acc[mi][ni][2] + bv);
                o.w = f2bf(acc[mi][ni][3] + bv);
                *(ushort4*)(vout + ((size_t)((b*H_ + h) * HD_ + hd)) * L_ + l) = o;
            } else {
                #pragma unroll
                for (int j = 0; j < 4; ++j) {
                    int m = mbase + j;
                    float v = acc[mi][ni][j];
                    if (MODE == 0) {
                        int b = m >> 11, l = m & 2047;
                        if (ncol < 2048) {
                            int h = ncol >> 7, hd = ncol & 127;
                            qout[((size_t)(b*H_ + h) * L_ + l) * HD_ + hd] = f2bf(v);
                        } else {
                            int cc = ncol - 2048, h = cc >> 7, hd = cc & 127;
                            kout[((size_t)(b*H_ + h) * L_ + l) * HD_ + hd] = f2bf(v);
                        }
                    } else {
                        fout[(size_t)m * N + ncol] = v + bias[ncol];
                    }
                }
            }
        }
    }
}

// ---------------------------------------------------------------- RMSNorm + RoPE
// Q rows additionally scaled by attn-scale * log2(e) for exp2-domain softmax.
__global__ __launch_bounds__(256) void k_normrope(unsigned short* __restrict__ qb,
                                                  unsigned short* __restrict__ kb,
                                                  const float* __restrict__ cosT,
                                                  const float* __restrict__ sinT,
                                                  const float* __restrict__ qw,
                                                  const float* __restrict__ kw) {
    const float QSCL = 0.08838834764831845f * 1.4426950408889634f;  // 1/sqrt(128) * log2(e)
    int lane = threadIdx.x & 63;
    int row = blockIdx.x * 4 + (threadIdx.x >> 6);
    int isK = row >= BH_ * L_;
    unsigned short* buf = isK ? kb : qb;
    const float* w = isK ? kw : qw;
    int r = isK ? row - BH_ * L_ : row;
    int l = r & (L_ - 1);
    unsigned short* p = buf + (size_t)r * HD_ + lane * 2;
    ushort2 u = *(const ushort2*)p;
    float x1 = bf2f(u.x), x2 = bf2f(u.y);
    float ss = x1*x1 + x2*x2;
    #pragma unroll
    for (int off = 32; off; off >>= 1) ss += __shfl_xor(ss, off);
    float rs = rsqrtf(ss * (1.0f / 128.0f) + 1e-6f);
    rs *= isK ? 1.0f : QSCL;
    float c = cosT[l * 64 + lane], s = sinT[l * 64 + lane];
    float y1 = x1 * rs * w[lane * 2];
    float y2 = x2 * rs * w[lane * 2 + 1];
    ushort2 o;
    o.x = f2bf(y1 * c - y2 * s);
    o.y = f2bf(y1 * s + y2 * c);
    *(ushort2*)p = o;
}

// ---------------------------------------------------------------- causal flash attention
// 128 q-rows/block, 4 waves, wave owns 32 rows. KV tile = 64; K+V staged together,
// 2 barriers/tile; 3 blocks/CU (50KB LDS, 152 VGPR). FIXED-BOUND exp2 softmax
// (P = 2^(S-20), no max/rescale). Ones-column MFMA row sums. T5 setprio.
#define PLDT 72

__global__ __launch_bounds__(256) void k_attn(const unsigned short* __restrict__ qbuf,
                                              const unsigned short* __restrict__ kbuf,
                                              const unsigned short* __restrict__ vT,
                                              unsigned short* __restrict__ yb) {
    __shared__ __align__(16) unsigned short Ks[64 * 128];
    __shared__ __align__(16) unsigned short Vs[128 * 64];
    __shared__ __align__(16) unsigned short Ps[4][32 * PLDT];
    int tid = threadIdx.x, lane = tid & 63, w = tid >> 6;
    int l15 = lane & 15, l4 = lane >> 4;
    int qb = 15 - (blockIdx.x >> 6);        // heavy blocks dispatched first
    int bh = blockIdx.x & 63;
    const unsigned short* Q  = qbuf + (size_t)bh * L_ * HD_;
    const unsigned short* Kp = kbuf + (size_t)bh * L_ * HD_;
    const unsigned short* Vp = vT   + (size_t)bh * L_ * HD_;
    int qr0 = qb * 128 + w * 32;

    bf16x8 qf[2][4];
    #pragma unroll
    for (int m = 0; m < 2; ++m)
        #pragma unroll
        for (int ks = 0; ks < 4; ++ks)
            qf[m][ks] = *(const bf16x8*)(Q + (size_t)(qr0 + m*16 + l15) * HD_ + ks*32 + l4*8);

    f32x4 accO[2][8] = {};
    f32x4 accW[2] = {};                      // ones-column row-sum accumulator

    bf16x8 vones;
    #pragma unroll
    for (int i = 0; i < 8; ++i) vones[i] = (__bf16)1.0f;

    const float BOUND = 20.0f;               // fixed softmax reference (log2 domain)
    int nkt = 2 * qb + 2;

    for (int kt = 0; kt < nkt; ++kt) {
        int kbase = kt * 64;
        #pragma unroll
        for (int i = 0; i < 4; ++i) {
            int g = w * 4 + i;
            int kr = g * 4 + (lane >> 4);
            gload16(Kp + (size_t)(kbase + kr) * HD_ + (((lane & 15) ^ (kr & 15)) << 3),
                    Ks + g * 512);
            int vr = g * 8 + (lane >> 3);
            gload16(Vp + (size_t)vr * L_ + kbase + (((lane & 7) ^ (vr & 7)) << 3),
                    Vs + g * 512);
        }
        __syncthreads();

        if (kbase <= qr0 + 31) {   // wave has at least one unmasked row in this tile
            // ---- S = Q K^T (log2 domain)
            f32x4 sf[2][4] = {};
            __builtin_amdgcn_s_setprio(1);
            #pragma unroll
            for (int f = 0; f < 4; ++f)
                #pragma unroll
                for (int ks = 0; ks < 4; ++ks) {
                    bf16x8 kf = *(const bf16x8*)(Ks + (f*16 + l15) * 128 +
                                                 ((((ks*4) + l4) ^ l15) << 3));
                    sf[0][f] = __builtin_amdgcn_mfma_f32_16x16x32_bf16(qf[0][ks], kf, sf[0][f], 0, 0, 0);
                    sf[1][f] = __builtin_amdgcn_mfma_f32_16x16x32_bf16(qf[1][ks], kf, sf[1][f], 0, 0, 0);
                }
            __builtin_amdgcn_s_setprio(0);

            // ---- P = 2^(S - BOUND) with causal mask -> per-wave LDS (A-frag layout)
            unsigned short* ps = Ps[w];
            #pragma unroll
            for (int m = 0; m < 2; ++m) {
                bool needmask = (kbase + 63 > qr0 + m*16);
                #pragma unroll
                for (int f = 0; f < 4; ++f)
                    #pragma unroll
                    for (int j = 0; j < 4; ++j) {
                        float s = sf[m][f][j];
                        if (needmask) {
                            int key  = kbase + f*16 + l15;
                            int qrow = qr0 + m*16 + l4*4 + j;
                            if (key > qrow) s = -1e30f;
                        }
                        float p = exp2f(s - BOUND);
                        *(__bf16*)(ps + (m*16 + l4*4 + j) * PLDT + f*16 + l15) = (__bf16)p;
                    }
            }

            // ---- O += P @ V, row-sum += P @ 1
            __builtin_amdgcn_s_setprio(1);
            #pragma unroll
            for (int ks = 0; ks < 2; ++ks) {
                bf16x8 pa0 = *(const bf16x8*)(ps + l15 * PLDT + ks*32 + l4*8);
                bf16x8 pa1 = *(const bf16x8*)(ps + (16 + l15) * PLDT + ks*32 + l4*8);
                #pragma unroll
                for (int cf = 0; cf < 8; ++cf) {
                    bf16x8 vf = *(const bf16x8*)(Vs + (cf*16 + l15) * 64 +
                                                 ((((ks*4) + l4) ^ (l15 & 7)) << 3));
                    accO[0][cf] = __builtin_amdgcn_mfma_f32_16x16x32_bf16(pa0, vf, accO[0][cf], 0, 0, 0);
                    accO[1][cf] = __builtin_amdgcn_mfma_f32_16x16x32_bf16(pa1, vf, accO[1][cf], 0, 0, 0);
                }
                accW[0] = __builtin_amdgcn_mfma_f32_16x16x32_bf16(pa0, vones, accW[0], 0, 0, 0);
                accW[1] = __builtin_amdgcn_mfma_f32_16x16x32_bf16(pa1, vones, accW[1], 0, 0, 0);
            }
            __builtin_amdgcn_s_setprio(0);
        }
        __syncthreads();
    }

    int b = bh >> 4, h = bh & 15;
    #pragma unroll
    for (int m = 0; m < 2; ++m)
        #pragma unroll
        for (int cf = 0; cf < 8; ++cf)
            #pragma unroll
            for (int j = 0; j < 4; ++j) {
                int qrow = qr0 + m*16 + l4*4 + j;
                float o = accO[m][cf][j] / accW[m][j];
                yb[((size_t)(b * L_ + qrow)) * D_ + h*128 + cf*16 + l15] = f2bf(o);
            }
}

// ---------------------------------------------------------------- launch
extern "C" void kernel_launch(void* const* d_in, const int* in_sizes, int n_in,
                              void* d_out, int out_size, void* d_ws, size_t ws_size,
                              hipStream_t stream) {
    const float* x    = (const float*)d_in[0];
    const float* fcos = (const float*)d_in[1];
    const float* fsin = (const float*)d_in[2];
    const float* Wqk  = (const float*)d_in[3];
    const float* Wv   = (const float*)d_in[4];
    const float* bv   = (const float*)d_in[5];
    const float* Wp   = (const float*)d_in[6];
    const float* bp   = (const float*)d_in[7];
    const float* qn_w = (const float*)d_in[8];
    const float* kn_w = (const float*)d_in[9];
    float* out = (float*)d_out;

    char* ws = (char*)d_ws;
    unsigned short* Wt   = (unsigned short*)(ws);                 // 6144x2048 bf16
    unsigned short* Wpt  = (unsigned short*)(ws + 25165824);      // 2048x2048 bf16
    unsigned short* xb   = (unsigned short*)(ws + 33554432);      // 8192x2048 bf16 (reused as yb)
    unsigned short* qbuf = (unsigned short*)(ws + 67108864);      // (BH,L,HD) bf16
    unsigned short* kbuf = (unsigned short*)(ws + 100663296);
    unsigned short* vTb  = (unsigned short*)(ws + 167772160);     // (BH,HD,L) bf16 (written directly by gemm<0>)
    unsigned short* yb   = xb;

    k_f32_to_bf16<<<8192, 256, 0, stream>>>(x, xb, BL_ * D_ / 8);
    k_transpose_f2b<<<dim3(128, 64), 256, 0, stream>>>(Wqk, Wt, 2048, 4096, 2048);
    k_transpose_f2b<<<dim3(64, 64),  256, 0, stream>>>(Wv,  Wt + (size_t)4096 * 2048, 2048, 2048, 2048);
    k_transpose_f2b<<<dim3(64, 64),  256, 0, stream>>>(Wp,  Wpt, 2048, 2048, 2048);

    k_gemm<0><<<dim3(24, 32), 512, 0, stream>>>(xb, Wt, BL_, 6144, 2048, bv,
                                                qbuf, kbuf, vTb, nullptr);
    k_normrope<<<2 * BH_ * L_ / 4, 256, 0, stream>>>(qbuf, kbuf, fcos, fsin, qn_w, kn_w);
    k_attn<<<BH_ * (L_ / 128), 256, 0, stream>>>(qbuf, kbuf, vTb, yb);
    k_gemm<1><<<dim3(8, 32), 512, 0, stream>>>(yb, Wpt, BL_, 2048, 2048, bp,
                                               nullptr, nullptr, nullptr, out);
}